// Round 1
// baseline (170.146 us; speedup 1.0000x reference)
//
#include <hip/hip_runtime.h>

// MLP_52759378264652: x[B,2] -> Linear(2,4)+ReLU -> 98x(Linear(4,4)+Sigmoid)
//                     -> Linear(4,1). B = 1048576, all fp32.
//
// Strategy: transcendental/VALU-bound problem (392 sigmoids/row dominates).
// - prep kernel: prescale W_mid,b_mid by -log2(e) into d_ws so sigmoid is
//   rcp(1 + exp2(y')) with no per-element scale mul (v_exp_f32 computes 2^x).
// - main kernel: R=4 rows/thread; per-layer weights are wave-uniform loads
//   from d_ws (expect s_load_dwordx4 into SGPRs -> zero VALU cost).

#define NMID 98
#define WS_PER_LAYER 20   // 16 W + 4 b, prescaled; 80 B per layer, 16B aligned

__global__ __launch_bounds__(256) void prep_kernel(
        const float* __restrict__ Wm, const float* __restrict__ bm,
        float* __restrict__ ws) {
    int e = blockIdx.x * blockDim.x + threadIdx.x;
    if (e >= NMID * WS_PER_LAYER) return;
    int l = e / WS_PER_LAYER;
    int r = e - l * WS_PER_LAYER;
    const float c = -1.44269504088896340736f;  // -log2(e)
    float v = (r < 16) ? Wm[l * 16 + r] : bm[l * 4 + (r - 16)];
    ws[e] = c * v;
}

template<int R>
__global__ __launch_bounds__(256) void mlp_kernel(
        const float* __restrict__ x,
        const float* __restrict__ W_in, const float* __restrict__ b_in,
        const float* __restrict__ W_out, const float* __restrict__ b_out,
        const float* __restrict__ wm,
        float* __restrict__ out, int B) {
    const int t = blockIdx.x * blockDim.x + threadIdx.x;
    const int stride = gridDim.x * blockDim.x;

    // stem weights (uniform -> SGPRs)
    float wi[8], bi[4];
    #pragma unroll
    for (int k = 0; k < 8; ++k) wi[k] = W_in[k];
    #pragma unroll
    for (int k = 0; k < 4; ++k) bi[k] = b_in[k];

    int rows[R];
    #pragma unroll
    for (int r = 0; r < R; ++r) rows[r] = t + r * stride;

    float h[R][4];
    #pragma unroll
    for (int r = 0; r < R; ++r) {
        float2 xv = make_float2(0.0f, 0.0f);
        if (rows[r] < B) xv = reinterpret_cast<const float2*>(x)[rows[r]];
        #pragma unroll
        for (int j = 0; j < 4; ++j) {
            float v = fmaf(wi[j*2+0], xv.x, fmaf(wi[j*2+1], xv.y, bi[j]));
            h[r][j] = fmaxf(v, 0.0f);
        }
    }

    // 98 x (Linear(4,4) + Sigmoid); weights prescaled by -log2(e)
    for (int l = 0; l < NMID; ++l) {
        const float* __restrict__ wl = wm + l * WS_PER_LAYER;
        float w[WS_PER_LAYER];
        #pragma unroll
        for (int k = 0; k < WS_PER_LAYER; ++k) w[k] = wl[k];
        #pragma unroll
        for (int r = 0; r < R; ++r) {
            float y[4];
            #pragma unroll
            for (int j = 0; j < 4; ++j) {
                y[j] = fmaf(w[j*4+0], h[r][0],
                       fmaf(w[j*4+1], h[r][1],
                       fmaf(w[j*4+2], h[r][2],
                       fmaf(w[j*4+3], h[r][3], w[16+j]))));
            }
            // sigmoid(v) = 1/(1+exp(-v)) ; y already = -log2(e)*v
            #pragma unroll
            for (int j = 0; j < 4; ++j) {
                h[r][j] = __builtin_amdgcn_rcpf(1.0f + __builtin_amdgcn_exp2f(y[j]));
            }
        }
    }

    // head: Linear(4,1)
    float wo[4];
    #pragma unroll
    for (int k = 0; k < 4; ++k) wo[k] = W_out[k];
    float bo = b_out[0];
    #pragma unroll
    for (int r = 0; r < R; ++r) {
        float o = fmaf(wo[0], h[r][0],
                  fmaf(wo[1], h[r][1],
                  fmaf(wo[2], h[r][2],
                  fmaf(wo[3], h[r][3], bo))));
        if (rows[r] < B) out[rows[r]] = o;
    }
}

extern "C" void kernel_launch(void* const* d_in, const int* in_sizes, int n_in,
                              void* d_out, int out_size, void* d_ws, size_t ws_size,
                              hipStream_t stream) {
    const float* x     = (const float*)d_in[0];
    const float* W_in  = (const float*)d_in[1];
    const float* b_in  = (const float*)d_in[2];
    const float* W_mid = (const float*)d_in[3];
    const float* b_mid = (const float*)d_in[4];
    const float* W_out = (const float*)d_in[5];
    const float* b_out = (const float*)d_in[6];
    float* out = (float*)d_out;
    float* ws  = (float*)d_ws;

    const int B = in_sizes[0] / 2;  // x is [B,2]

    // prescale mid-layer weights into workspace (re-done every call: d_ws is
    // re-poisoned by the harness before each timed launch)
    hipLaunchKernelGGL(prep_kernel, dim3((NMID * WS_PER_LAYER + 255) / 256),
                       dim3(256), 0, stream, W_mid, b_mid, ws);

    constexpr int R = 4;
    const int threads = 256;
    const int grid = (B + threads * R - 1) / (threads * R);  // 1024 for B=1M
    hipLaunchKernelGGL((mlp_kernel<R>), dim3(grid), dim3(threads), 0, stream,
                       x, W_in, b_in, W_out, b_out, ws, out, B);
}